// Round 13
// baseline (72.077 us; speedup 1.0000x reference)
//
#include <hip/hip_runtime.h>

#define DD 40
#define SLM1 9
#define ANUM 268
#define MB 16
#define PST 72    // p/ae row stride (u16)
#define RST 82    // red row stride (f32) - breaks 4-way bank aliasing

typedef __attribute__((ext_vector_type(8))) short short8;
typedef __attribute__((ext_vector_type(4))) float f32x4;

// ws offsets (u16). 16x16x32 B-frag layout (field-verified r2):
// within 1024-u16 (tile,frag) chunk: i -> frag=i>>9, l=(i&511)>>3, j=i&7;
// k = frag*32 + 8*(l>>4) + j ; col = base + (l&15).
#define WS_LW ((size_t)0)          // ((s*40+d)*3 + et)*1024
#define WS_QW ((size_t)1105920)    // s*3072 + et*1024
#define WS_MW ((size_t)1133568)    // s*3072 + et*1024
#define WS_TW ((size_t)1161216)    // t*1024, t=0..16
// total 1178624 u16 = 2.36 MB

__device__ __forceinline__ unsigned short f2bf(float f){
  unsigned int u = __float_as_uint(f);
  u += 0x7FFFu + ((u >> 16) & 1u);
  return (unsigned short)(u >> 16);
}
__device__ __forceinline__ float relu6f(float v){
  return fminf(fmaxf(v, 0.0f), 6.0f);
}
__device__ __forceinline__ f32x4 mfma2(short8 a0, short8 a1, short8 b0, short8 b1){
  f32x4 c = {0.f, 0.f, 0.f, 0.f};
  c = __builtin_amdgcn_mfma_f32_16x16x32_bf16(a0, b0, c, 0, 0, 0);
  c = __builtin_amdgcn_mfma_f32_16x16x32_bf16(a1, b1, c, 0, 0, 0);
  return c;
}

__global__ __launch_bounds__(256)
void prep_frags(const float* __restrict__ Qw, const float* __restrict__ Lw,
                const float* __restrict__ Mw, const float* __restrict__ Tw,
                const float* __restrict__ Ew, const float* __restrict__ Eb,
                const float* __restrict__ Qb, const float* __restrict__ Lb,
                const float* __restrict__ Mb, const float* __restrict__ Tb,
                unsigned short* __restrict__ ws)
{
  const int bid = blockIdx.x, tid = threadIdx.x;
  if (bid < 360){                       // Lw: one block per (s,d): 3 et-tiles
    int s = bid / 40, d = bid - s*40;
    unsigned short* dst = ws + WS_LW + (size_t)bid*3072;
    const float* W = Lw + (size_t)s*64000;
    const float* bv = Lb + (size_t)s*1600;
    for (int i = tid; i < 3072; i += 256){
      int et = i >> 10, r = i & 1023, frag = r >> 9, q = r & 511, l = q >> 3, j = q & 7;
      int k = frag*32 + ((l >> 4) << 3) + j;
      int e = et*16 + (l & 15);
      float v = 0.f;
      if (e < DD){
        int n = d*DD + e;
        if (k < DD) v = W[n*DD + k];
        else if (k == DD) v = bv[n];        // Lb at k=40
      }
      dst[i] = f2bf(v);
    }
  } else if (bid < 369){                // Qw (+Eb+Qb at k=40, Ew at k=41)
    int s = bid - 360;
    unsigned short* dst = ws + WS_QW + (size_t)s*3072;
    const float* W = Qw + (size_t)s*1600;
    for (int i = tid; i < 3072; i += 256){
      int et = i >> 10, r = i & 1023, frag = r >> 9, q = r & 511, l = q >> 3, j = q & 7;
      int k = frag*32 + ((l >> 4) << 3) + j;
      int jc = et*16 + (l & 15);
      float v = 0.f;
      if (jc < DD){
        if (k < DD) v = W[jc*DD + k];
        else if (k == DD) v = Eb[s*DD + jc] + Qb[s*DD + jc];
        else if (k == DD+1) v = Ew[s*DD + jc];
      }
      dst[i] = f2bf(v);
    }
  } else if (bid < 378){                // Mw (+Mb at k=40)
    int s = bid - 369;
    unsigned short* dst = ws + WS_MW + (size_t)s*3072;
    const float* W = Mw + (size_t)s*1600;
    for (int i = tid; i < 3072; i += 256){
      int et = i >> 10, r = i & 1023, frag = r >> 9, q = r & 511, l = q >> 3, j = q & 7;
      int k = frag*32 + ((l >> 4) << 3) + j;
      int e = et*16 + (l & 15);
      float v = 0.f;
      if (e < DD){
        if (k < DD) v = W[e*DD + k];
        else if (k == DD) v = Mb[s*DD + e];
      }
      dst[i] = f2bf(v);
    }
  } else {                              // Tw tiles t=0..16 (+Tb at k=40)
    int t = bid - 378;
    unsigned short* dst = ws + WS_TW + (size_t)t*1024;
    for (int i = tid; i < 1024; i += 256){
      int frag = i >> 9, q = i & 511, l = q >> 3, j = q & 7;
      int k = frag*32 + ((l >> 4) << 3) + j;
      int a = t*16 + (l & 15);
      float v = 0.f;
      if (a < ANUM){
        if (k < DD) v = Tw[(size_t)a*DD + k];
        else if (k == DD) v = Tb[a];
      }
      dst[i] = f2bf(v);
    }
  }
}

// MB=16, 512 thr / 8 waves, grid 512 -> 2 blocks/CU (16 waves/CU, 4/SIMD).
// 16x16x32 MFMA, K=64 (bias k=40, tvec k=41). LDS padded into the
// (54.6, 81.9] KB window -> 128-VGPR budget (r10/r12 anchor).
// Per step: B(s) all 8 waves (5 d x 3 e-tiles) | bar |
//           AC: waves0-2 A(s+1), waves3-5 C(s) | bar.
__global__ __launch_bounds__(512)
void star_main(const int* __restrict__ X,
               const int* __restrict__ T1,
               const int* __restrict__ T2,
               const float* __restrict__ emb,
               const unsigned short* __restrict__ ws,
               float* __restrict__ out)
{
  __shared__ __align__(16) unsigned short pbuf[2][MB*PST]; // p-state row-major [m][k]
  __shared__ __align__(16) unsigned short aebf[2][MB*PST]; // emb gather row-major
  __shared__ __align__(16) float hT[2][DD*20];             // h-state [d][m]
  __shared__ __align__(16) float red[8][MB*RST];           // tt partials per wave
  __shared__ int   aeidx[SLM1][MB];
  __shared__ float tvtab[SLM1][MB];

  const int tid = threadIdx.x;
  const int w = __builtin_amdgcn_readfirstlane(tid >> 6);
  const int l = tid & 63;
  const int lr = l & 15;        // col / row index within 16-tile
  const int lg = l >> 4;        // 0..3 (k-group / row-group)
  const int row0 = blockIdx.x * MB;

  // ---- prologue ----
  {
    unsigned int* p = (unsigned int*)&pbuf[0][0];
    for (int i = tid; i < MB*PST; i += 512) p[i] = 0u;       // both pbuf (2*1152 u16 = 1152 u32)
    unsigned int* a = (unsigned int*)&aebf[0][0];
    for (int i = tid; i < MB*PST; i += 512) a[i] = 0u;
    float* ht = &hT[0][0];
    for (int i = tid; i < 2*DD*20; i += 512) ht[i] = 0.f;
    float* rr = &red[0][0];
    for (int i = tid; i < 8*MB*RST; i += 512) rr[i] = 0.f;   // C(0) sums zeros
  }
  if (tid < MB*SLM1){
    int m = tid / SLM1, s = tid - m*SLM1;
    int r = row0 + m;
    aeidx[s][m] = X[(size_t)r*40 + s*4 + 3];
    tvtab[s][m] = (float)(T1[r*SLM1 + s]*8 + T2[r*SLM1 + s]);
  }
  __syncthreads();
  if (tid < MB){
    pbuf[0][tid*PST + 40] = 0x3F80;  pbuf[1][tid*PST + 40] = 0x3F80;  // bias mult
    aebf[0][tid*PST + 40] = 0x3F80;  aebf[1][tid*PST + 40] = 0x3F80;
    pbuf[0][tid*PST + 41] = f2bf(tvtab[0][tid]);
    pbuf[1][tid*PST + 41] = f2bf(tvtab[1][tid]);
  }
  if (tid < 160){   // gather ae(0), row-major
    int m = tid / 10, q4 = tid - m*10;
    float4 v4 = *(const float4*)(emb + (size_t)aeidx[0][m]*DD + q4*4);
    unsigned short* dst = &aebf[0][m*PST + q4*4];
    dst[0]=f2bf(v4.x); dst[1]=f2bf(v4.y); dst[2]=f2bf(v4.z); dst[3]=f2bf(v4.w);
  }
  __syncthreads();
  // A(0): waves 0-2, et = w
  if (w < 3){
    short8 a0 = *(const short8*)&pbuf[0][lr*PST + (lg << 3)];
    short8 a1 = *(const short8*)&pbuf[0][lr*PST + 32 + (lg << 3)];
    const unsigned short* qwb = ws + WS_QW + (size_t)w*1024;
    f32x4 c = mfma2(a0, a1, ((const short8*)qwb)[l], ((const short8*)(qwb+512))[l]);
    int e = w*16 + lr;
    if (e < DD){
      #pragma unroll
      for (int r = 0; r < 4; ++r)
        pbuf[1][((lg << 2) + r)*PST + e] = f2bf(relu6f(c[r]));
    }
  }
  __syncthreads();

  for (int s = 0; s < SLM1; ++s){
    const int pcur = (s + 1) & 1;   // buffer holding p1(s)
    const int hrd  = s & 1;

    // ---- B phase ----
    float4 gv; int gm = 0, gq = 0;
    const bool dog = (s < 8) && (tid < 160);
    if (dog){
      gm = tid / 10; gq = tid - gm*10;
      gv = *(const float4*)(emb + (size_t)aeidx[s+1][gm]*DD + gq*4);
    }
    if (s > 0){
      short8 pa0 = *(const short8*)&pbuf[pcur][lr*PST + (lg << 3)];
      short8 pa1 = *(const short8*)&pbuf[pcur][lr*PST + 32 + (lg << 3)];
      const unsigned short* lwb = ws + WS_LW + (size_t)(s*40)*3072;
      f32x4 tt0 = {0,0,0,0}, tt1 = {0,0,0,0}, tt2 = {0,0,0,0};
      #pragma unroll
      for (int i = 0; i < 5; ++i){
        const int d = i*8 + w;
        const unsigned short* fb = lwb + (size_t)d*3072;
        short8 b00 = ((const short8*)fb)[l];
        short8 b01 = ((const short8*)(fb +  512))[l];
        short8 b10 = ((const short8*)(fb + 1024))[l];
        short8 b11 = ((const short8*)(fb + 1536))[l];
        short8 b20 = ((const short8*)(fb + 2048))[l];
        short8 b21 = ((const short8*)(fb + 2560))[l];
        f32x4 c0 = mfma2(pa0, pa1, b00, b01);
        f32x4 c1 = mfma2(pa0, pa1, b10, b11);
        f32x4 c2 = mfma2(pa0, pa1, b20, b21);
        f32x4 hg = *(const f32x4*)&hT[hrd][d*20 + (lg << 2)];
        #pragma unroll
        for (int r = 0; r < 4; ++r){
          tt0[r] = fmaf(hg[r], relu6f(c0[r]), tt0[r]);
          tt1[r] = fmaf(hg[r], relu6f(c1[r]), tt1[r]);
          tt2[r] = fmaf(hg[r], relu6f(c2[r]), tt2[r]);
        }
      }
      #pragma unroll
      for (int r = 0; r < 4; ++r){
        int m = (lg << 2) + r;
        red[w][m*RST + lr]      = tt0[r];
        red[w][m*RST + 16 + lr] = tt1[r];
        if (lr < 8) red[w][m*RST + 32 + lr] = tt2[r];
      }
    }
    // late writes
    if (dog){
      unsigned short* dst = &aebf[(s+1) & 1][gm*PST + gq*4];
      dst[0]=f2bf(gv.x); dst[1]=f2bf(gv.y); dst[2]=f2bf(gv.z); dst[3]=f2bf(gv.w);
    }
    if (s <= 6 && tid < MB)
      pbuf[s & 1][tid*PST + 41] = f2bf(tvtab[s+2][tid]);
    __syncthreads();

    // ---- AC phase ----
    if (w < 3){
      if (s < 8){   // A(s+1), et = w
        short8 a0 = *(const short8*)&pbuf[pcur][lr*PST + (lg << 3)];
        short8 a1 = *(const short8*)&pbuf[pcur][lr*PST + 32 + (lg << 3)];
        const unsigned short* qwb = ws + WS_QW + (size_t)(s+1)*3072 + (size_t)w*1024;
        f32x4 c = mfma2(a0, a1, ((const short8*)qwb)[l], ((const short8*)(qwb+512))[l]);
        int e = w*16 + lr;
        if (e < DD){
          #pragma unroll
          for (int r = 0; r < 4; ++r)
            pbuf[s & 1][((lg << 2) + r)*PST + e] = f2bf(relu6f(c[r]));
        }
      }
    } else if (w < 6){   // C(s), et = w-3
      const int et = w - 3;
      const int e = et*16 + lr;
      f32x4 c = {0,0,0,0};
      if (e < DD){
        #pragma unroll
        for (int r = 0; r < 4; ++r){
          int m = (lg << 2) + r;
          float acc = red[0][m*RST + e];
          #pragma unroll
          for (int dp = 1; dp < 8; ++dp) acc += red[dp][m*RST + e];
          c[r] = acc;
        }
      }
      short8 a0 = *(const short8*)&aebf[s & 1][lr*PST + (lg << 3)];
      short8 a1 = *(const short8*)&aebf[s & 1][lr*PST + 32 + (lg << 3)];
      const unsigned short* mwb = ws + WS_MW + (size_t)s*3072 + (size_t)et*1024;
      c = __builtin_amdgcn_mfma_f32_16x16x32_bf16(a0, ((const short8*)mwb)[l], c, 0, 0, 0);
      c = __builtin_amdgcn_mfma_f32_16x16x32_bf16(a1, ((const short8*)(mwb+512))[l], c, 0, 0, 0);
      if (e < DD){
        #pragma unroll
        for (int r = 0; r < 4; ++r){
          int m = (lg << 2) + r;
          float v = relu6f(c[r]);
          hT[(s+1) & 1][e*20 + m] = v;
          if (s == SLM1-1) pbuf[0][m*PST + e] = f2bf(v);  // h-final (col40 bias preserved)
        }
      }
    }
    __syncthreads();
  }

  // ---- epilogue: out = h@Tw^T + Tb (h in pbuf[0], Tb folded at k=40) ----
  for (int t = w; t < 17; t += 8){
    short8 a0 = *(const short8*)&pbuf[0][lr*PST + (lg << 3)];
    short8 a1 = *(const short8*)&pbuf[0][lr*PST + 32 + (lg << 3)];
    const unsigned short* twb = ws + WS_TW + (size_t)t*1024;
    f32x4 c = mfma2(a0, a1, ((const short8*)twb)[l], ((const short8*)(twb+512))[l]);
    int a = t*16 + lr;
    if (a < ANUM){
      #pragma unroll
      for (int r = 0; r < 4; ++r)
        out[(size_t)(row0 + (lg << 2) + r)*ANUM + a] = c[r];
    }
  }
}

extern "C" void kernel_launch(void* const* d_in, const int* in_sizes, int n_in,
                              void* d_out, int out_size, void* d_ws, size_t ws_size,
                              hipStream_t stream) {
  const int*   X  = (const int*)  d_in[0];
  const int*   T1 = (const int*)  d_in[1];
  const int*   T2 = (const int*)  d_in[2];
  const float* Ew = (const float*)d_in[3];
  const float* Eb = (const float*)d_in[4];
  const float* Qw = (const float*)d_in[5];
  const float* Qb = (const float*)d_in[6];
  const float* Lw = (const float*)d_in[7];
  const float* Lb = (const float*)d_in[8];
  const float* Mw = (const float*)d_in[9];
  const float* Mb = (const float*)d_in[10];
  const float* Tw = (const float*)d_in[11];
  const float* Tb = (const float*)d_in[12];
  const float* em = (const float*)d_in[13];
  unsigned short* ws = (unsigned short*)d_ws;
  float* out = (float*)d_out;

  prep_frags<<<dim3(395), dim3(256), 0, stream>>>(Qw, Lw, Mw, Tw, Ew, Eb, Qb,
                                                  Lb, Mb, Tb, ws);
  star_main<<<dim3(8192 / MB), dim3(512), 0, stream>>>(X, T1, T2, em, ws, out);
}

// Round 14
// 57.317 us; speedup vs baseline: 1.2575x; 1.2575x over previous
//
#include <hip/hip_runtime.h>

#define DD 40
#define SLM1 9
#define ANUM 268
#define MB 32

typedef __attribute__((ext_vector_type(8))) short short8;
typedef __attribute__((ext_vector_type(4))) float f32x4;
typedef __attribute__((ext_vector_type(16))) float f32x16;

// ws offsets (u16 units)
#define WS_LWF ((size_t)0)        // full tiles: (s*40+d)*1536 ; e=0..31
#define WS_LWT ((size_t)552960)   // tail tiles: (s*10+t)*1536 ; col c -> d=4t+(c>>3), e=32+(c&7)
#define WS_QW  ((size_t)691200)   // s*3072 (+ et*1536)
#define WS_MW  ((size_t)718848)   // s*3072
#define WS_TW  ((size_t)746496)   // t*1536

__device__ __forceinline__ unsigned short f2bf(float f){
  unsigned int u = __float_as_uint(f);
  u += 0x7FFFu + ((u >> 16) & 1u);
  return (unsigned short)(u >> 16);
}
__device__ __forceinline__ float relu6f(float v){
  return fminf(fmaxf(v, 0.0f), 6.0f);
}

__device__ __forceinline__ f32x16 mfma3(short8 a0, short8 a1, short8 a2,
                                        short8 b0, short8 b1, short8 b2){
  f32x16 c = {0,0,0,0,0,0,0,0,0,0,0,0,0,0,0,0};
  c = __builtin_amdgcn_mfma_f32_32x32x16_bf16(a0, b0, c, 0, 0, 0);
  c = __builtin_amdgcn_mfma_f32_32x32x16_bf16(a1, b1, c, 0, 0, 0);
  c = __builtin_amdgcn_mfma_f32_32x32x16_bf16(a2, b2, c, 0, 0, 0);
  return c;
}

// Build 32x32x16 MFMA B-fragments with bias rows folded into K-pad slots.
// B layout: col = l&31, k = 8*(l>>5)+j (+16*kf).  (verified r3-r12)
__global__ __launch_bounds__(256)
void prep_frags(const float* __restrict__ Qw, const float* __restrict__ Lw,
                const float* __restrict__ Mw, const float* __restrict__ Tw,
                const float* __restrict__ Ew, const float* __restrict__ Eb,
                const float* __restrict__ Qb, const float* __restrict__ Lb,
                const float* __restrict__ Mb, const float* __restrict__ Tb,
                unsigned short* __restrict__ ws)
{
  const int bid = blockIdx.x, tid = threadIdx.x;
  if (bid < 360){                       // Lw full tiles (e 0..31), one per (s,d)
    int s = bid / 40, d = bid - s*40;
    unsigned short* dst = ws + WS_LWF + (size_t)bid*1536;
    const float* W = Lw + (size_t)s*64000;
    const float* bv = Lb + (size_t)s*1600;
    for (int i = tid; i < 1536; i += 256){
      int kf = i >> 9, q = i & 511, l = q >> 3, j = q & 7;
      int k = kf*16 + ((l >> 5) << 3) + j;
      int e = l & 31;
      int n = d*DD + e;
      float v = 0.f;
      if (k < DD) v = W[n*DD + k];
      else if (k == DD) v = bv[n];
      dst[i] = f2bf(v);
    }
  } else if (bid < 450){                // Lw tail tiles (e 32..39, 4 d's packed)
    int t = bid - 360;
    int s = t / 10, tt = t - s*10;
    unsigned short* dst = ws + WS_LWT + (size_t)t*1536;
    const float* W = Lw + (size_t)s*64000;
    const float* bv = Lb + (size_t)s*1600;
    for (int i = tid; i < 1536; i += 256){
      int kf = i >> 9, q = i & 511, l = q >> 3, j = q & 7;
      int k = kf*16 + ((l >> 5) << 3) + j;
      int c = l & 31;
      int d = 4*tt + (c >> 3);
      int e = 32 + (c & 7);
      int n = d*DD + e;
      float v = 0.f;
      if (k < DD) v = W[n*DD + k];
      else if (k == DD) v = bv[n];
      dst[i] = f2bf(v);
    }
  } else if (bid < 459){                // Qw (+Eb+Qb at k=40, Ew at k=41)
    int s = bid - 450;
    unsigned short* dst = ws + WS_QW + (size_t)s*3072;
    const float* W = Qw + (size_t)s*1600;
    for (int i = tid; i < 3072; i += 256){
      int et = i / 1536, r = i - et*1536;
      int kf = r >> 9, q = r & 511, l = q >> 3, j = q & 7;
      int k = kf*16 + ((l >> 5) << 3) + j;
      int jc = et*32 + (l & 31);
      float v = 0.f;
      if (jc < DD){
        if (k < DD) v = W[jc*DD + k];
        else if (k == DD) v = Eb[s*DD + jc] + Qb[s*DD + jc];
        else if (k == DD+1) v = Ew[s*DD + jc];
      }
      dst[i] = f2bf(v);
    }
  } else if (bid < 468){                // Mw (+Mb at k=40)
    int s = bid - 459;
    unsigned short* dst = ws + WS_MW + (size_t)s*3072;
    const float* W = Mw + (size_t)s*1600;
    for (int i = tid; i < 3072; i += 256){
      int et = i / 1536, r = i - et*1536;
      int kf = r >> 9, q = r & 511, l = q >> 3, j = q & 7;
      int k = kf*16 + ((l >> 5) << 3) + j;
      int e = et*32 + (l & 31);
      float v = 0.f;
      if (e < DD){
        if (k < DD) v = W[e*DD + k];
        else if (k == DD) v = Mb[s*DD + e];
      }
      dst[i] = f2bf(v);
    }
  } else {                              // Tw (+Tb at k=40)
    int t = bid - 468;
    unsigned short* dst = ws + WS_TW + (size_t)t*1536;
    for (int i = tid; i < 1536; i += 256){
      int kf = i >> 9, q = i & 511, l = q >> 3, j = q & 7;
      int k = kf*16 + ((l >> 5) << 3) + j;
      int a = t*32 + (l & 31);
      float v = 0.f;
      if (a < ANUM){
        if (k < DD) v = Tw[(size_t)a*DD + k];
        else if (k == DD) v = Tb[a];
      }
      dst[i] = f2bf(v);
    }
  }
}

// r12 base (58.1us) + latency cuts (r13 MB=16 regressed -> reverted):
//  - A(s+1) moved into phase 1 on waves 6,7 (phase 2 = C only)
//  - cross-step prefetch: next step's first 2 b-triplets loaded into regs
//    that persist across the barrier (kills per-step d-loop cold start)
//  - tails on waves 0-5 (stride 6)
__global__ __launch_bounds__(512)
void star_main(const int* __restrict__ X,
               const int* __restrict__ T1,
               const int* __restrict__ T2,
               const float* __restrict__ emb,
               const unsigned short* __restrict__ ws,
               float* __restrict__ out)
{
  __shared__ __align__(16) unsigned short pbuf[2][3072]; // p-state, A-frag order
  __shared__ __align__(16) unsigned short aebf[2][3072]; // emb gather (dbuf); [1] = final h
  __shared__ __align__(16) float hT[2][DD*36];           // h-state, [d][m]
  __shared__ __align__(16) float red[8][MB*DD];          // tt partials per wave
  __shared__ int   aeidx[SLM1][MB];
  __shared__ float tvtab[SLM1][MB];

  const int tid = threadIdx.x;
  const int w = __builtin_amdgcn_readfirstlane(tid >> 6);
  const int l = tid & 63;
  const int col = l & 31, half = l >> 5;
  const int row0 = blockIdx.x * MB;

  // ---- prologue ----
  {
    unsigned int* p = (unsigned int*)&pbuf[0][0];
    for (int i = tid; i < 3072; i += 512) p[i] = 0u;
    unsigned int* a = (unsigned int*)&aebf[0][0];
    for (int i = tid; i < 3072; i += 512) a[i] = 0u;
    float* rr = &red[0][0];
    for (int i = tid; i < 8*MB*DD; i += 512) rr[i] = 0.f;  // C(0) sums zeros
  }
  if (tid < MB*SLM1){
    int m = tid / SLM1, s = tid - m*SLM1;
    int r = row0 + m;
    aeidx[s][m] = X[(size_t)r*40 + s*4 + 3];
    tvtab[s][m] = (float)(T1[r*SLM1 + s]*8 + T2[r*SLM1 + s]);
  }
  __syncthreads();
  if (tid < MB){
    int off = 2*1024 + (tid + 32)*8;    // k=40 (bias mult), k=41 (tvec)
    pbuf[0][off] = 0x3F80; pbuf[1][off] = 0x3F80;
    aebf[0][off] = 0x3F80; aebf[1][off] = 0x3F80;
    pbuf[0][off+1] = f2bf(tvtab[0][tid]);
    pbuf[1][off+1] = f2bf(tvtab[1][tid]);
  }
  if (tid < 320){  // gather ae(0)
    int m = tid / 10, q4 = tid - m*10;
    float4 v4 = *(const float4*)(emb + (size_t)aeidx[0][m]*DD + q4*4);
    #pragma unroll
    for (int c2 = 0; c2 < 4; ++c2){
      int k = q4*4 + c2, kf = k >> 4, kk = k & 15;
      aebf[0][kf*1024 + (m + ((kk >> 3) << 5))*8 + (kk & 7)] = f2bf(((const float*)&v4)[c2]);
    }
  }
  __syncthreads();
  // A(0): p1(0) = relu6(0@Qw + t*Ew + Eb + Qb), waves 0,1
  if (w < 2){
    short8 a0 = ((const short8*)&pbuf[0][0])[l];
    short8 a1 = ((const short8*)&pbuf[0][1024])[l];
    short8 a2 = ((const short8*)&pbuf[0][2048])[l];
    const unsigned short* qwb = ws + WS_QW + w*1536;
    f32x16 c = mfma3(a0, a1, a2, ((const short8*)qwb)[l],
                     ((const short8*)(qwb+512))[l], ((const short8*)(qwb+1024))[l]);
    int j = w*32 + col;
    if (j < DD){
      int kf = j >> 4, kk = j & 15;
      #pragma unroll
      for (int r = 0; r < 16; ++r){
        int m = (r & 3) + ((r >> 2) << 3) + (half << 2);
        pbuf[1][kf*1024 + (m + ((kk >> 3) << 5))*8 + (kk & 7)] = f2bf(relu6f(c[r]));
      }
    }
  }
  __syncthreads();

  // cross-step prefetch regs: next step's first two full-tile triplets
  short8 q00, q01, q02, q10, q11, q12;

  for (int s = 0; s < SLM1; ++s){
    const int pcur = (s + 1) & 1;   // buffer holding p1(s)
    const int hrd  = s & 1;

    // ---- phase 1: B(s) (all waves) + A(s+1) (waves 6,7) ----
    float4 gv; int gm = 0, gq = 0;
    const bool dog = (s < 8) && (tid < 320);
    if (dog){
      gm = tid / 10; gq = tid - gm*10;
      gv = *(const float4*)(emb + (size_t)aeidx[s+1][gm]*DD + gq*4);
    }
    short8 pa0 = ((const short8*)&pbuf[pcur][0])[l];
    short8 pa1 = ((const short8*)&pbuf[pcur][1024])[l];
    short8 pa2 = ((const short8*)&pbuf[pcur][2048])[l];
    if (s > 0){
      const float* hbase = &hT[hrd][half << 2];

      // full tiles: d = i*8+w; first two triplets come from the cross-step
      // prefetch regs (loaded last step, in flight across the barrier)
      f32x16 tt = {0,0,0,0,0,0,0,0,0,0,0,0,0,0,0,0};
      {
        const unsigned short* lwf = ws + WS_LWF + (size_t)(s*40)*1536;
        short8 b00 = q00, b01 = q01, b02 = q02;
        short8 b10 = q10, b11 = q11, b12 = q12;
        #pragma unroll
        for (int i = 0; i < 5; ++i){
          short8 nb0, nb1, nb2;
          if (i < 3){
            const unsigned short* nf = lwf + (size_t)((i+2)*8 + w)*1536;
            nb0 = ((const short8*)nf)[l];
            nb1 = ((const short8*)(nf + 512))[l];
            nb2 = ((const short8*)(nf + 1024))[l];
          }
          // hoist h reads ahead of the MFMAs (LDS latency under MFMA)
          const float* hb = hbase + (i*8 + w)*36;
          f32x4 h0 = *(const f32x4*)(hb);
          f32x4 h1 = *(const f32x4*)(hb + 8);
          f32x4 h2 = *(const f32x4*)(hb + 16);
          f32x4 h3 = *(const f32x4*)(hb + 24);
          f32x16 c = mfma3(pa0, pa1, pa2, b00, b01, b02);
          #pragma unroll
          for (int q = 0; q < 4; ++q){
            tt[q]    = fmaf(h0[q], relu6f(c[q]),    tt[q]);
            tt[4+q]  = fmaf(h1[q], relu6f(c[4+q]),  tt[4+q]);
            tt[8+q]  = fmaf(h2[q], relu6f(c[8+q]),  tt[8+q]);
            tt[12+q] = fmaf(h3[q], relu6f(c[12+q]), tt[12+q]);
          }
          b00 = b10; b01 = b11; b02 = b12;
          if (i < 3){ b10 = nb0; b11 = nb1; b12 = nb2; }
        }
      }
      // commit full-tile partials (plain stores, per-wave slice)
      #pragma unroll
      for (int r = 0; r < 16; ++r){
        int m = (r & 3) + ((r >> 2) << 3) + (half << 2);
        red[w][m*DD + col] = tt[r];
      }
    }

    // cross-step prefetch for step s+1 (issued before tails/A so the loads
    // are in flight through phase 2 + barrier)
    if (s < 8){
      const unsigned short* nl = ws + WS_LWF + (size_t)((s+1)*40)*1536;
      const unsigned short* n0 = nl + (size_t)w*1536;
      q00 = ((const short8*)n0)[l];
      q01 = ((const short8*)(n0 + 512))[l];
      q02 = ((const short8*)(n0 + 1024))[l];
      const unsigned short* n1 = nl + (size_t)(8 + w)*1536;
      q10 = ((const short8*)n1)[l];
      q11 = ((const short8*)(n1 + 512))[l];
      q12 = ((const short8*)(n1 + 1024))[l];
    }

    if (s > 0 && w < 6){
      // packed tail tiles on waves 0-5: tile t covers d=4t+(col>>3), e=32+(col&7)
      const unsigned short* lwt = ws + WS_LWT + (size_t)(s*10)*1536;
      f32x16 tacc = {0,0,0,0,0,0,0,0,0,0,0,0,0,0,0,0};
      for (int tti = w; tti < 10; tti += 6){
        const unsigned short* ft = lwt + (size_t)tti*1536;
        short8 t0 = ((const short8*)ft)[l];
        short8 t1 = ((const short8*)(ft + 512))[l];
        short8 t2 = ((const short8*)(ft + 1024))[l];
        f32x16 c = mfma3(pa0, pa1, pa2, t0, t1, t2);
        int dt = 4*tti + (col >> 3);
        const float* hb = &hT[hrd][dt*36 + (half << 2)];
        #pragma unroll
        for (int g = 0; g < 4; ++g){
          f32x4 hg = *(const f32x4*)(hb + g*8);
          #pragma unroll
          for (int q = 0; q < 4; ++q){
            float val = hg[q]*relu6f(c[g*4+q]);
            val += __shfl_xor(val, 8);
            val += __shfl_xor(val, 16);
            tacc[g*4+q] += val;
          }
        }
      }
      if (col < 8){
        #pragma unroll
        for (int r = 0; r < 16; ++r){
          int m = (r & 3) + ((r >> 2) << 3) + (half << 2);
          red[w][m*DD + 32 + col] = tacc[r];
        }
      }
    } else if (w >= 6 && s < 8){
      // A(s+1) on waves 6,7 (reads p1(s) + tvec(s+1); writes pbuf[s&1])
      const int et = w - 6;
      const unsigned short* qwb = ws + WS_QW + (size_t)(s+1)*3072 + (size_t)et*1536;
      f32x16 c = mfma3(pa0, pa1, pa2, ((const short8*)qwb)[l],
                       ((const short8*)(qwb+512))[l], ((const short8*)(qwb+1024))[l]);
      int j = et*32 + col;
      if (j < DD){
        int kf = j >> 4, kk = j & 15;
        #pragma unroll
        for (int r = 0; r < 16; ++r){
          int m = (r & 3) + ((r >> 2) << 3) + (half << 2);
          pbuf[s & 1][kf*1024 + (m + ((kk >> 3) << 5))*8 + (kk & 7)] = f2bf(relu6f(c[r]));
        }
      }
    }
    // late writes: ae(s+1); tvec(s+2) into pbuf[s&1] k=41 (A(s+2) reads it;
    // B(s+1) multiplies k=41 against Lw's zero row -> no hazard; A(s+1) above
    // writes only rows m<32 of the kf=2 block, tvec uses rows 32+ -> disjoint)
    if (dog){
      unsigned short* dst = &aebf[(s+1) & 1][0];
      #pragma unroll
      for (int c2 = 0; c2 < 4; ++c2){
        int k = gq*4 + c2, kf = k >> 4, kk = k & 15;
        dst[kf*1024 + (gm + ((kk >> 3) << 5))*8 + (kk & 7)] = f2bf(((const float*)&gv)[c2]);
      }
    }
    if (s <= 6 && tid < MB)
      pbuf[s & 1][2*1024 + (tid + 32)*8 + 1] = f2bf(tvtab[s+2][tid]);
    __syncthreads();

    // ---- phase 2: C(s) only (waves 0,1) ----
    if (w < 2){
      short8 a0 = ((const short8*)&aebf[s & 1][0])[l];
      short8 a1 = ((const short8*)&aebf[s & 1][1024])[l];
      short8 a2 = ((const short8*)&aebf[s & 1][2048])[l];
      const unsigned short* mwb = ws + WS_MW + (size_t)s*3072 + w*1536;
      int e = w*32 + col;
      f32x16 c = {0,0,0,0,0,0,0,0,0,0,0,0,0,0,0,0};
      if (e < DD){
        #pragma unroll
        for (int r = 0; r < 16; ++r){
          int m = (r & 3) + ((r >> 2) << 3) + (half << 2);
          float acc = red[0][m*DD + e];
          #pragma unroll
          for (int dp = 1; dp < 8; ++dp) acc += red[dp][m*DD + e];
          c[r] = acc;
        }
      }
      c = __builtin_amdgcn_mfma_f32_32x32x16_bf16(a0, ((const short8*)mwb)[l], c, 0, 0, 0);
      c = __builtin_amdgcn_mfma_f32_32x32x16_bf16(a1, ((const short8*)(mwb+512))[l], c, 0, 0, 0);
      c = __builtin_amdgcn_mfma_f32_32x32x16_bf16(a2, ((const short8*)(mwb+1024))[l], c, 0, 0, 0);
      if (e < DD){
        int kf = e >> 4, kk = e & 15;
        #pragma unroll
        for (int r = 0; r < 16; ++r){
          int m = (r & 3) + ((r >> 2) << 3) + (half << 2);
          float v = relu6f(c[r]);
          hT[(s+1) & 1][e*36 + m] = v;
          if (s == SLM1-1)
            aebf[1][kf*1024 + (m + ((kk >> 3) << 5))*8 + (kk & 7)] = f2bf(v);
        }
      }
    }
    __syncthreads();
  }

  // ---- epilogue: out = h@Tw^T + Tb via MFMA (h-frag in aebf[1]) ----
  for (int t = w; t < 9; t += 8){
    short8 a0 = ((const short8*)&aebf[1][0])[l];
    short8 a1 = ((const short8*)&aebf[1][1024])[l];
    short8 a2 = ((const short8*)&aebf[1][2048])[l];
    const unsigned short* twb = ws + WS_TW + (size_t)t*1536;
    f32x16 c = mfma3(a0, a1, a2, ((const short8*)twb)[l],
                     ((const short8*)(twb+512))[l], ((const short8*)(twb+1024))[l]);
    int a = t*32 + col;
    if (a < ANUM){
      #pragma unroll
      for (int r = 0; r < 16; ++r){
        int m = (r & 3) + ((r >> 2) << 3) + (half << 2);
        out[(size_t)(row0 + m)*ANUM + a] = c[r];
      }
    }
  }
}

extern "C" void kernel_launch(void* const* d_in, const int* in_sizes, int n_in,
                              void* d_out, int out_size, void* d_ws, size_t ws_size,
                              hipStream_t stream) {
  const int*   X  = (const int*)  d_in[0];
  const int*   T1 = (const int*)  d_in[1];
  const int*   T2 = (const int*)  d_in[2];
  const float* Ew = (const float*)d_in[3];
  const float* Eb = (const float*)d_in[4];
  const float* Qw = (const float*)d_in[5];
  const float* Qb = (const float*)d_in[6];
  const float* Lw = (const float*)d_in[7];
  const float* Lb = (const float*)d_in[8];
  const float* Mw = (const float*)d_in[9];
  const float* Mb = (const float*)d_in[10];
  const float* Tw = (const float*)d_in[11];
  const float* Tb = (const float*)d_in[12];
  const float* em = (const float*)d_in[13];
  unsigned short* ws = (unsigned short*)d_ws;
  float* out = (float*)d_out;

  prep_frags<<<dim3(477), dim3(256), 0, stream>>>(Qw, Lw, Mw, Tw, Ew, Eb, Qb,
                                                  Lb, Mb, Tb, ws);
  star_main<<<dim3(8192 / MB), dim3(512), 0, stream>>>(X, T1, T2, em, ws, out);
}